// Round 1
// baseline (430.611 us; speedup 1.0000x reference)
//
#include <hip/hip_runtime.h>

// shuffleAug: composition of 5 per-sample affine flips/transpose collapses to
//   out[b,c,i,j] = in[b,c, sA*p+tA, sC*q+tC],  (p,q) = swap ? (j,i) : (i,j)
// Pure permutation -> memory-bound tile copy through LDS (handles the
// transpose case with coalesced loads AND stores).

#define HWDIM 128
#define TILE  32
#define BCNT  32
#define CHALF 64

__global__ __launch_bounds__(256) void shuffle_aug_kernel(
    const float* __restrict__ x1,
    const float* __restrict__ x2,
    const int*   __restrict__ flips,   // (5, 32) int32
    float*       __restrict__ out)     // x1_out flat then x2_out flat
{
    __shared__ float lds[TILE][TILE + 1];   // +1 pad: conflict-free transpose reads

    const int bid  = blockIdx.x;
    const int tile = bid & 15;            // 4x4 tiles of a 128x128 plane
    const int ct   = (bid >> 4) & 127;    // concatenated channel 0..127
    const int b    = bid >> 11;           // sample 0..31

    const int f0 = flips[0 * BCNT + b];
    const int f1 = flips[1 * BCNT + b];
    const int f2 = flips[2 * BCNT + b];   // swap
    const int f3 = flips[3 * BCNT + b];
    const int f4 = flips[4 * BCNT + b];

    // step4 (flipX on i) and step5 (flipY on j), outermost first:
    int sI = f3 ? -1 : 1, tI = f3 ? 127 : 0;
    int sJ = f4 ? -1 : 1, tJ = f4 ? 127 : 0;
    // then swap, then step2 (flipY -> c), step1 (flipX -> a):
    int sA, tA, sC, tC;
    if (f2) {
        sA = f0 ? -sJ : sJ;  tA = f0 ? 127 - tJ : tJ;   // a = sA*j + tA
        sC = f1 ? -sI : sI;  tC = f1 ? 127 - tI : tI;   // c = sC*i + tC
    } else {
        sA = f0 ? -sI : sI;  tA = f0 ? 127 - tI : tI;   // a = sA*i + tA
        sC = f1 ? -sJ : sJ;  tC = f1 ? 127 - tJ : tJ;   // c = sC*j + tC
    }

    const int ti = tile >> 2, tj = tile & 3;
    const int i0 = ti * TILE, j0 = tj * TILE;
    const int p0 = f2 ? j0 : i0;          // range feeding a
    const int q0 = f2 ? i0 : j0;          // range feeding c
    // (sA,tA) is always (1,0) or (-1,127) -> aMin/cMin are multiples of 32
    const int aMin = (sA > 0) ? (p0 + tA) : (tA - (p0 + TILE - 1));
    const int cMin = (sC > 0) ? (q0 + tC) : (tC - (q0 + TILE - 1));

    const int cLoc = ct & (CHALF - 1);
    const size_t plane = (size_t)(b * CHALF + cLoc) * (HWDIM * HWDIM);
    const float* __restrict__ src = (ct < CHALF ? x1 : x2) + plane;
    float* __restrict__ dst = out
        + (ct < CHALF ? (size_t)0 : (size_t)BCNT * CHALF * HWDIM * HWDIM)
        + plane;

    const int t   = threadIdx.x;
    const int vx  = t & 7;     // float4 column within tile (0..7)
    const int row = t >> 3;    // tile row (0..31)

    // --- load input tile [aMin, aMin+32) x [cMin, cMin+32), coalesced ---
    const float4 v = *reinterpret_cast<const float4*>(
        &src[(size_t)(aMin + row) * HWDIM + cMin + vx * 4]);
    lds[row][vx * 4 + 0] = v.x;
    lds[row][vx * 4 + 1] = v.y;
    lds[row][vx * 4 + 2] = v.z;
    lds[row][vx * 4 + 3] = v.w;

    __syncthreads();

    // --- write output tile, coalesced float4 stores ---
    const int i = i0 + row;
    float4 o;
    {
        const int jb = j0 + vx * 4;
        const int q  = f2 ? i : 0;       // helpers resolved per element below
        (void)q;
        float ov[4];
#pragma unroll
        for (int e = 0; e < 4; ++e) {
            const int j  = jb + e;
            const int p  = f2 ? j : i;
            const int qq = f2 ? i : j;
            const int a  = sA * p + tA;
            const int c  = sC * qq + tC;
            ov[e] = lds[a - aMin][c - cMin];
        }
        o.x = ov[0]; o.y = ov[1]; o.z = ov[2]; o.w = ov[3];
    }
    *reinterpret_cast<float4*>(&dst[(size_t)i * HWDIM + j0 + vx * 4]) = o;
}

extern "C" void kernel_launch(void* const* d_in, const int* in_sizes, int n_in,
                              void* d_out, int out_size, void* d_ws, size_t ws_size,
                              hipStream_t stream) {
    const float* x1    = (const float*)d_in[0];
    const float* x2    = (const float*)d_in[1];
    const int*   flips = (const int*)d_in[2];
    float*       out   = (float*)d_out;

    const int grid = BCNT * (2 * CHALF) * 16;   // 32 * 128 * 16 = 65536 tiles
    shuffle_aug_kernel<<<grid, 256, 0, stream>>>(x1, x2, flips, out);
}